// Round 2
// baseline (1818.331 us; speedup 1.0000x reference)
//
#include <hip/hip_runtime.h>

// Problem constants
#define NND 8192   // nodes
#define FD  32     // feature dim
#define ED  32     // embedding dim
#define SUP 4      // relations
#define NB  2      // bases

// rgcn_main tiling
#define BROWS 256              // output rows per block
#define TK    16               // k per LDS step (64 B/row)
#define KSPLIT 8               // k-chunks per relation
#define CHUNK (NND / KSPLIT)   // 1024
#define NSTEP (CHUNK / TK)     // 64

#define FMA4(acc, sa, g) { acc.x += (sa) * (g).x; acc.y += (sa) * (g).y; \
                           acc.z += (sa) * (g).z; acc.w += (sa) * (g).w; }

// Direct global->LDS 16B staging. LDS dest is wave-uniform base + lane*16
// (strictly linear); the A bank-de-conflict swizzle is applied on the GLOBAL
// source granule and identically on the LDS read side (both-sides-or-neither).
#define GLDS16(gsrc, ldst) \
  __builtin_amdgcn_global_load_lds((const __attribute__((address_space(1))) void*)(gsrc), \
                                   (__attribute__((address_space(3))) void*)(ldst), 16, 0, 0)

// --------------------------------------------------------------------------
// Kernel 1: G[s][m][e] = sum_f features[m][f] * Veff[s][f][e], and zero out.
// One thread per (s,m). Veff[s][f][e] = sum_b Wc[f&3][b] * W[b][s*8+f/4][e].
// --------------------------------------------------------------------------
__global__ __launch_bounds__(256) void prep_g(
        const float* __restrict__ features,
        const float* __restrict__ W,
        const float* __restrict__ Wc,
        float* __restrict__ G,
        float* __restrict__ out) {
    __shared__ __align__(16) float Vlds[FD * ED];   // 4 KB: this block's s only
    const int t   = threadIdx.x;
    const int gid = blockIdx.x * 256 + t;           // 0..32767
    const int s   = gid >> 13;                      // uniform within a block
    const int m   = gid & (NND - 1);

    for (int i = t; i < FD * ED; i += 256) {
        const int e  = i & 31;
        const int f  = i >> 5;
        const int f2 = s * 8 + (f >> 2);
        const int s2 = f & 3;
        float v = 0.f;
        #pragma unroll
        for (int b = 0; b < NB; ++b)
            v += Wc[s2 * NB + b] * W[(b * FD + f2) * ED + e];
        Vlds[i] = v;
    }
    __syncthreads();

    // Zero the output accumulator (65536 float4 over 32768 threads)
    float4* out4 = (float4*)out;
    const float4 z = {0.f, 0.f, 0.f, 0.f};
    out4[gid]         = z;
    out4[gid + 32768] = z;

    const float4* feat4 = (const float4*)(features + (size_t)m * FD);
    float4 fr[8];
    #pragma unroll
    for (int i = 0; i < 8; ++i) fr[i] = feat4[i];

    float4 acc[8];
    #pragma unroll
    for (int i = 0; i < 8; ++i) acc[i] = z;

    const float4* V4 = (const float4*)Vlds;         // broadcast reads (free)
    #pragma unroll
    for (int f = 0; f < FD; ++f) {
        const float fv = ((const float*)fr)[f];     // static index (unrolled)
        #pragma unroll
        for (int e4 = 0; e4 < 8; ++e4) {
            const float4 v = V4[f * 8 + e4];
            FMA4(acc[e4], fv, v);
        }
    }
    float4* g4 = (float4*)(G + ((size_t)s * NND + m) * ED);
    #pragma unroll
    for (int e4 = 0; e4 < 8; ++e4) g4[e4] = acc[e4];
}

// --------------------------------------------------------------------------
// Kernel 2: out[n][e] += sum_{m in chunk} A[s][n][m] * G[s][m][e]
// 256 threads (4 waves), tile 256 rows x 32 e, per-thread 4 rows x 8 e.
// Rows per thread strided 64 apart; A granules XOR-swizzled (source+read)
// so the A ds_read_b128 is a free 2-way bank alias. 36 KB LDS -> 4 blocks/CU
// = 4 waves/SIMD. stage(t+1) issued before compute(t); one barrier/step.
// --------------------------------------------------------------------------
__global__ __launch_bounds__(256, 4) void rgcn_main(
        const float* __restrict__ A,
        const float* __restrict__ G,
        float* __restrict__ out) {
    __shared__ __align__(16) float Asb[2][BROWS * TK];  // 2 x 16 KB
    __shared__ __align__(16) float Gsb[2][TK * ED];     // 2 x 2 KB   -> 36 KB

    const int t  = threadIdx.x;
    const int bx = blockIdx.x;           // 1024 blocks
    const int nb = bx & 31;              // 32 n-blocks
    const int kb = bx >> 5;              // 32 (s, k-chunk) combos
    const int s       = kb >> 3;         // relation
    const int m_start = (kb & 7) * CHUNK;
    const int n0      = nb * BROWS;

    const float* Ab = A + ((size_t)s * NND + n0) * NND + m_start;
    const float* Gb = G + (size_t)s * NND * ED + (size_t)m_start * ED;

    const int w    = t >> 6;             // wave 0..3
    const int lane = t & 63;

    // Stage: A tile 256 rows x 16 floats (16 insts, 4/wave), G tile 16x32 (2 insts).
    // Source granule for (row, slot): slot ^ ((row>>1)&3); row = inst*16 + (lane>>2)
    // => sg = (lane&3) ^ ((lane>>3)&3), identical for all insts.
    const int rowi = lane >> 2;
    const int sg   = (lane & 3) ^ ((lane >> 3) & 3);
    auto stage = [&](int step, int buf) {
        const int m0 = step * TK;
        #pragma unroll
        for (int i = 0; i < 4; ++i) {
            const int inst = w * 4 + i;
            const int row  = inst * 16 + rowi;
            GLDS16(Ab + (size_t)row * NND + m0 + (sg << 2), &Asb[buf][inst * 256]);
        }
        if (w < 2)
            GLDS16(Gb + (size_t)m0 * ED + w * 256 + lane * 4, &Gsb[buf][w * 256]);
    };

    // Compute mapping: rg = t>>2 (0..63) -> rows rg + 64*i; eg = t&3 -> e = eg*8..+7
    const int rg = t >> 2;
    const int eg = t & 3;
    const int sr = (rg >> 1) & 3;        // read-side granule XOR (= (row>>1)&3, all i)

    float4 acc[4][2];
    #pragma unroll
    for (int i = 0; i < 4; ++i) {
        acc[i][0] = float4{0.f, 0.f, 0.f, 0.f};
        acc[i][1] = float4{0.f, 0.f, 0.f, 0.f};
    }

    stage(0, 0);
    __syncthreads();                      // drains stage(0) (vmcnt 0) + sync

    for (int step = 0; step < NSTEP; ++step) {
        const int buf = step & 1;
        if (step + 1 < NSTEP) stage(step + 1, buf ^ 1);   // loads fly during compute

        const float* As = Asb[buf];
        const float* Gs = Gsb[buf];
        #pragma unroll
        for (int k4 = 0; k4 < TK / 4; ++k4) {   // 4 k per iter
            const float4 a0 = *(const float4*)&As[(rg +   0) * TK + ((k4 ^ sr) << 2)];
            const float4 a1 = *(const float4*)&As[(rg +  64) * TK + ((k4 ^ sr) << 2)];
            const float4 a2 = *(const float4*)&As[(rg + 128) * TK + ((k4 ^ sr) << 2)];
            const float4 a3 = *(const float4*)&As[(rg + 192) * TK + ((k4 ^ sr) << 2)];
            #define KSTEP(kk, comp) { \
                const float4 g0 = *(const float4*)&Gs[(k4 * 4 + kk) * ED + eg * 8]; \
                const float4 g1 = *(const float4*)&Gs[(k4 * 4 + kk) * ED + eg * 8 + 4]; \
                FMA4(acc[0][0], a0.comp, g0); FMA4(acc[0][1], a0.comp, g1); \
                FMA4(acc[1][0], a1.comp, g0); FMA4(acc[1][1], a1.comp, g1); \
                FMA4(acc[2][0], a2.comp, g0); FMA4(acc[2][1], a2.comp, g1); \
                FMA4(acc[3][0], a3.comp, g0); FMA4(acc[3][1], a3.comp, g1); }
            KSTEP(0, x) KSTEP(1, y) KSTEP(2, z) KSTEP(3, w)
            #undef KSTEP
        }
        // Drains this step's prefetch and guarantees all waves finished reading
        // buf before the next iteration's stage overwrites it.
        __syncthreads();
    }

    // Epilogue: 32 split-K contributions per output element (4 s x 8 chunks)
    #pragma unroll
    for (int i = 0; i < 4; ++i) {
        float* p = out + (size_t)(n0 + rg + 64 * i) * ED + eg * 8;
        atomicAdd(p + 0, acc[i][0].x);
        atomicAdd(p + 1, acc[i][0].y);
        atomicAdd(p + 2, acc[i][0].z);
        atomicAdd(p + 3, acc[i][0].w);
        atomicAdd(p + 4, acc[i][1].x);
        atomicAdd(p + 5, acc[i][1].y);
        atomicAdd(p + 6, acc[i][1].z);
        atomicAdd(p + 7, acc[i][1].w);
    }
}

extern "C" void kernel_launch(void* const* d_in, const int* in_sizes, int n_in,
                              void* d_out, int out_size, void* d_ws, size_t ws_size,
                              hipStream_t stream) {
    const float* features = (const float*)d_in[0];
    const float* A        = (const float*)d_in[1];
    const float* W        = (const float*)d_in[2];
    const float* Wc       = (const float*)d_in[3];
    float* out = (float*)d_out;
    float* G   = (float*)d_ws;   // 4*8192*32 floats = 4 MB

    prep_g<<<128, 256, 0, stream>>>(features, W, Wc, G, out);
    rgcn_main<<<32 * KSPLIT * SUP, 256, 0, stream>>>(A, G, out);
}